// Round 3
// baseline (212.447 us; speedup 1.0000x reference)
//
#include <hip/hip_runtime.h>
#include <hip/hip_bf16.h>

#define BB 64
#define SS 400
#define HH 512
#define EE 300
#define VV 50000
#define KD 812     // E+H (LSTM input width)
#define KG 1324    // 2H+E (gen_in width)
#define KC 1024    // 2H (out_cat width)
#define BV (BB*VV)
#define KCH 128    // gemm K-chunk (f32 elements per row per chunk)

typedef __attribute__((ext_vector_type(8))) short bf16x8;
typedef __attribute__((ext_vector_type(4))) float f32x4;
typedef __attribute__((address_space(1))) const void gv_t;
typedef __attribute__((address_space(3))) void lv_t;

// ---- workspace layout (float offsets) ----
#define WS_SCORE 0                       // [B*S]
#define WS_W     25600                   // [B*S]
#define WS_DINT  51200                   // [1324][64]
#define WS_CTX   135936                  // [64][512]
#define WS_HNEW  168704                  // [64][512]
#define WS_GA0   201472                  // [2048][64] x4 partial gate buffers
#define WS_GA1   332544
#define WS_GB0   463616
#define WS_GB1   594688
#define WS_PGEN  725760                  // [64]
#define WS_ABF   725888                  // ushort [64][1024] bf16 out_cat (byte 2903552, 16B aligned)
#define WS_PART  758656                  // [64][8][512] ctx partials

__device__ __forceinline__ float sigm(float x){ return 1.f/(1.f+__expf(-x)); }
__device__ __forceinline__ float ftanh(float x){
  x = fminf(fmaxf(x,-15.f),15.f);
  float e = __expf(2.f*x);
  return (e-1.f)/(e+1.f);
}
__device__ __forceinline__ unsigned short f2bf(float f){
  unsigned int u = __builtin_bit_cast(unsigned int, f);
  u += 0x7fffu + ((u>>16)&1u);
  return (unsigned short)(u>>16);
}

// K0: embedding gather -> dinT rows [0,300); h_prev transpose -> dinT rows [812,1324)
__global__ __launch_bounds__(256) void k_prep(const int* __restrict__ x,
    const float* __restrict__ emb, const float* __restrict__ h0,
    float* __restrict__ dinT)
{
  int n = blockIdx.x*256 + threadIdx.x;
  if (n < BB*EE){
    int b = n/EE, e = n - b*EE;
    dinT[e*BB + b] = emb[(size_t)x[b]*EE + e];
  } else {
    int m = n - BB*EE;
    int b = m >> 9, h = m & (HH-1);
    dinT[(KD + h)*BB + b] = h0[b*HH + h];
  }
}

// K1: score[b,s] = V_w . tanh(enc[b,s,:] + h_prev[b,:]) + V_b
__global__ __launch_bounds__(256) void k_score(const float* __restrict__ enc,
    const float* __restrict__ h0, const float* __restrict__ Vw,
    const float* __restrict__ Vb, float* __restrict__ score)
{
  int wv = threadIdx.x >> 6, lane = threadIdx.x & 63;
  int pair = blockIdx.x*4 + wv;
  int b = pair / SS;
  int i0 = lane*8;
  const float4* ep = (const float4*)(enc + (size_t)pair*HH + i0);
  const float4* hp = (const float4*)(h0 + b*HH + i0);
  const float4* vp = (const float4*)(Vw + i0);
  float4 e0 = ep[0], e1 = ep[1];
  float4 hv0 = hp[0], hv1 = hp[1];
  float4 v0 = vp[0], v1 = vp[1];
  float sum = ftanh(e0.x+hv0.x)*v0.x + ftanh(e0.y+hv0.y)*v0.y
            + ftanh(e0.z+hv0.z)*v0.z + ftanh(e0.w+hv0.w)*v0.w
            + ftanh(e1.x+hv1.x)*v1.x + ftanh(e1.y+hv1.y)*v1.y
            + ftanh(e1.z+hv1.z)*v1.z + ftanh(e1.w+hv1.w)*v1.w;
  #pragma unroll
  for (int off=32; off; off>>=1) sum += __shfl_xor(sum, off);
  if (lane==0) score[pair] = sum + Vb[0];
}

// K2: per (b, s-chunk): recompute softmax over full row, partial ctx over 50 s (float2 loads).
__global__ __launch_bounds__(256) void k_ctx(const float* __restrict__ enc,
    const float* __restrict__ score, float* __restrict__ wout,
    float* __restrict__ part)
{
  __shared__ float red[256];
  __shared__ float wl[SS];
  int b = blockIdx.x >> 3, sp = blockIdx.x & 7;
  int t = threadIdx.x;
  float v1 = score[b*SS + t];
  float v2 = (t < SS-256) ? score[b*SS + t + 256] : -1e30f;
  red[t] = fmaxf(v1, v2);
  __syncthreads();
  for (int o=128; o; o>>=1){ if (t<o) red[t] = fmaxf(red[t], red[t+o]); __syncthreads(); }
  float mx = red[0];
  __syncthreads();
  float e1 = __expf(v1 - mx);
  float e2 = (t < SS-256) ? __expf(v2 - mx) : 0.f;
  red[t] = e1 + e2;
  __syncthreads();
  for (int o=128; o; o>>=1){ if (t<o) red[t] += red[t+o]; __syncthreads(); }
  float inv = 1.f/red[0];
  float w1 = e1*inv;
  wl[t] = w1;
  if (sp==0) wout[b*SS + t] = w1;
  if (t < SS-256){
    float w2 = e2*inv;
    wl[t+256] = w2;
    if (sp==0) wout[b*SS + t + 256] = w2;
  }
  __syncthreads();
  float a0 = 0.f, a1 = 0.f;
  const float* ebase = enc + ((size_t)b*SS + sp*50)*HH + 2*t;
  #pragma unroll 5
  for (int s=0; s<50; ++s){
    float wg = wl[sp*50 + s];
    float2 e = *(const float2*)(ebase + s*HH);
    a0 += wg * e.x;
    a1 += wg * e.y;
  }
  *(float2*)(part + (size_t)(b*8+sp)*HH + 2*t) = make_float2(a0, a1);
}

// K3: reduce 8 ctx partials; write ctx and ctx^T into dinT
__global__ __launch_bounds__(256) void k_ctx_reduce(const float* __restrict__ part,
    float* __restrict__ ctx, float* __restrict__ dinT)
{
  int b = blockIdx.x, t = threadIdx.x;
  float a0=0.f, a1=0.f;
  #pragma unroll
  for (int sp=0; sp<8; ++sp){
    float2 e = *(const float2*)(part + (size_t)(b*8+sp)*HH + 2*t);
    a0 += e.x; a1 += e.y;
  }
  *(float2*)(ctx + b*HH + 2*t) = make_float2(a0, a1);
  dinT[(EE + 2*t)*BB + b]     = a0;
  dinT[(EE + 2*t + 1)*BB + b] = a1;
}

// K4: gate partials. 2048 waves: 512 gate-quads x 4 K-quarters.
__global__ __launch_bounds__(256) void k_gates(const float* __restrict__ Wih,
    const float* __restrict__ Whh, const float* __restrict__ dinT,
    float* __restrict__ g0, float* __restrict__ g1,
    float* __restrict__ g2, float* __restrict__ g3)
{
  int lane = threadIdx.x & 63;
  int wg = blockIdx.x*4 + (threadIdx.x >> 6);     // 0..2047
  int jg = __builtin_amdgcn_readfirstlane(wg >> 2);
  int q  = __builtin_amdgcn_readfirstlane(wg & 3);
  int j0 = jg*4;
  float a0=0.f,a1=0.f,a2=0.f,a3=0.f;
  if (q < 2){
    const float* w0 = Wih + (size_t)j0*KD;
    int k0 = q ? 406 : 0, k1 = q ? 812 : 406;
    #pragma unroll 2
    for (int k=k0; k<k1; ++k){
      float d = dinT[k*BB + lane];
      a0 += w0[k]*d; a1 += w0[KD+k]*d; a2 += w0[2*KD+k]*d; a3 += w0[3*KD+k]*d;
    }
    float* g = q ? g1 : g0;
    g[(j0+0)*BB+lane]=a0; g[(j0+1)*BB+lane]=a1; g[(j0+2)*BB+lane]=a2; g[(j0+3)*BB+lane]=a3;
  } else {
    const float* w0 = Whh + (size_t)j0*HH;
    int k0 = (q==3) ? 256 : 0, k1 = (q==3) ? 512 : 256;
    #pragma unroll 4
    for (int k=k0; k<k1; ++k){
      float d = dinT[(KD+k)*BB + lane];
      a0 += w0[k]*d; a1 += w0[HH+k]*d; a2 += w0[2*HH+k]*d; a3 += w0[3*HH+k]*d;
    }
    float* g = (q==3) ? g3 : g2;
    g[(j0+0)*BB+lane]=a0; g[(j0+1)*BB+lane]=a1; g[(j0+2)*BB+lane]=a2; g[(j0+3)*BB+lane]=a3;
  }
}

// K5: LSTM cell elementwise
__global__ __launch_bounds__(256) void k_lstm(const float* __restrict__ c0,
    const float* __restrict__ bih, const float* __restrict__ bhh,
    const float* __restrict__ g0, const float* __restrict__ g1,
    const float* __restrict__ g2, const float* __restrict__ g3,
    const float* __restrict__ ctx, float* __restrict__ hnew,
    unsigned short* __restrict__ abf, float* __restrict__ out)
{
  int n = blockIdx.x*256 + threadIdx.x;   // < 32768
  int b = n & 63, h = n >> 6;
  #define GSUM(off) (g0[(off)*BB+b] + g1[(off)*BB+b] + g2[(off)*BB+b] + g3[(off)*BB+b] + bih[off] + bhh[off])
  float gi = GSUM(h);
  float gf = GSUM(HH+h);
  float gg = GSUM(2*HH+h);
  float go = GSUM(3*HH+h);
  #undef GSUM
  float cn = sigm(gf)*c0[b*HH+h] + sigm(gi)*ftanh(gg);
  float hn = sigm(go)*ftanh(cn);
  out[BV + b*HH + h]          = hn;
  out[BV + BB*HH + b*HH + h]  = cn;
  hnew[b*HH + h] = hn;
  abf[b*KC + h]      = f2bf(hn);
  abf[b*KC + HH + h] = f2bf(ctx[b*HH + h]);
}

// K6: p_gen[b]
__global__ __launch_bounds__(256) void k_pgen(const float* __restrict__ genw,
    const float* __restrict__ genb, const float* __restrict__ ctx,
    const float* __restrict__ hnew, const float* __restrict__ dinT,
    float* __restrict__ pgen)
{
  __shared__ float red[256];
  int b = blockIdx.x, t = threadIdx.x;
  float p = 0.f;
  for (int k=t; k<KG; k+=256){
    float g = genw[k];
    float v = (k < HH) ? ctx[b*HH + k]
            : (k < 2*HH) ? hnew[b*HH + k - HH]
            : dinT[(k - 2*HH)*BB + b];
    p += g*v;
  }
  red[t] = p; __syncthreads();
  for (int o=128; o; o>>=1){ if (t<o) red[t] += red[t+o]; __syncthreads(); }
  if (t==0) pgen[b] = sigm(red[0] + genb[0]);
}

// K7: out[b,v] = pgen[b]*(out_cat . out_w[v,:] + out_b[v]).
// T3 2-phase template: async global_load_lds (f32 weights, 16B width) into
// double-buffered LDS with pre-swizzled source (rule #21), swizzled
// ds_read_b128 + in-register cvt_pk -> bf16 MFMA. Wave wv owns M-tile wv
// (16 batches); block owns one 16-v-col tile, K chunked by 128.
__global__ __launch_bounds__(256, 4) void k_gemm(const float* __restrict__ out_w,
    const float* __restrict__ out_b, const unsigned short* __restrict__ abf,
    const float* __restrict__ pgen, float* __restrict__ out)
{
  __shared__ __align__(16) float wlds[2][16*KCH];   // 2 x 8 KB
  int vt = blockIdx.x;                               // 0..3124
  int t  = threadIdx.x;
  int wv = t >> 6, lane = t & 63;
  int col = lane & 15, kg = lane >> 4;
  const float* wbase = out_w + (size_t)vt*16*KC;
  const unsigned short* arow = abf + (size_t)(wv*16 + col)*KC + kg*8;

  // DMA one chunk: 8 segments of 1 KB (2 rows each); wave wv does segs 2wv, 2wv+1.
  // LDS linear slot j of row r holds global slot j^(r&7)  (XOR involution).
  #define STAGE(c_, buf_) { \
    _Pragma("unroll") \
    for (int si=0; si<2; ++si){ \
      int s_ = wv*2 + si; \
      int row_ = s_*2 + (lane>>5); \
      int j_ = lane & 31; \
      const float* gp_ = wbase + (size_t)row_*KC + (c_)*KCH + ((j_ ^ (row_&7))<<2); \
      __builtin_amdgcn_global_load_lds((gv_t*)gp_, (lv_t*)&wlds[buf_][s_*256], 16, 0, 0); \
    } }

  f32x4 acc = {0.f,0.f,0.f,0.f};
  bf16x8 pa[2][4];

  STAGE(0, 0);
  #pragma unroll
  for (int ks=0; ks<4; ++ks)
    pa[0][ks] = *(const bf16x8*)(arow + ks*32);
  __syncthreads();

  int row512 = col*512;            // B-frag row base (bytes) in LDS
  int sw = (col&7)<<4;             // read-side XOR swizzle

  #pragma unroll
  for (int c=0; c<8; ++c){
    if (c < 7){
      STAGE(c+1, (c+1)&1);
      #pragma unroll
      for (int ks=0; ks<4; ++ks)
        pa[(c+1)&1][ks] = *(const bf16x8*)(arow + (c+1)*KCH + ks*32);
    }
    const char* rb = (const char*)&wlds[c&1][0] + row512;
    #pragma unroll
    for (int ks=0; ks<4; ++ks){
      int off = ks*128 + kg*32;
      float4 f0 = *(const float4*)(rb + ((off     ) ^ sw));
      float4 f1 = *(const float4*)(rb + ((off + 16) ^ sw));
      union { bf16x8 v; unsigned int u[4]; } bb;
      asm("v_cvt_pk_bf16_f32 %0, %1, %2" : "=v"(bb.u[0]) : "v"(f0.x), "v"(f0.y));
      asm("v_cvt_pk_bf16_f32 %0, %1, %2" : "=v"(bb.u[1]) : "v"(f0.z), "v"(f0.w));
      asm("v_cvt_pk_bf16_f32 %0, %1, %2" : "=v"(bb.u[2]) : "v"(f1.x), "v"(f1.y));
      asm("v_cvt_pk_bf16_f32 %0, %1, %2" : "=v"(bb.u[3]) : "v"(f1.z), "v"(f1.w));
      acc = __builtin_amdgcn_mfma_f32_16x16x32_bf16(pa[c&1][ks], bb.v, acc, 0,0,0);
    }
    __syncthreads();
  }
  #undef STAGE

  float ob = out_b[vt*16 + col];
  #pragma unroll
  for (int i=0;i<4;i++){
    int b = wv*16 + kg*4 + i;
    out[(size_t)b*VV + vt*16 + col] = pgen[b]*(acc[i] + ob);
  }
}

// K8: pointer scatter, last-duplicate-wins.
__global__ __launch_bounds__(256) void k_scatter(const int* __restrict__ text,
    const float* __restrict__ w, const float* __restrict__ pgen,
    float* __restrict__ out)
{
  int n = blockIdx.x*256 + threadIdx.x;
  if (n >= BB*SS) return;
  int b = n / SS, s = n - b*SS;
  const int* trow = text + b*SS;
  int v = trow[s];
  for (int s2 = s+1; s2 < SS; ++s2)
    if (trow[s2] == v) return;
  out[(size_t)b*VV + v] += (1.f - pgen[b]) * w[n];
}

extern "C" void kernel_launch(void* const* d_in, const int* in_sizes, int n_in,
                              void* d_out, int out_size, void* d_ws, size_t ws_size,
                              hipStream_t stream)
{
  const int*   x    = (const int*)  d_in[0];
  const float* enc  = (const float*)d_in[1];
  const float* h0   = (const float*)d_in[2];
  const float* c0   = (const float*)d_in[3];
  const int*   text = (const int*)  d_in[4];
  const float* emb  = (const float*)d_in[6];
  const float* Vw   = (const float*)d_in[7];
  const float* Vb   = (const float*)d_in[8];
  const float* genw = (const float*)d_in[9];
  const float* genb = (const float*)d_in[10];
  const float* outw = (const float*)d_in[11];
  const float* outb = (const float*)d_in[12];
  const float* Wih  = (const float*)d_in[13];
  const float* Whh  = (const float*)d_in[14];
  const float* bih  = (const float*)d_in[15];
  const float* bhh  = (const float*)d_in[16];
  float* out = (float*)d_out;

  float* ws     = (float*)d_ws;
  float* score  = ws + WS_SCORE;
  float* wbuf   = ws + WS_W;
  float* dinT   = ws + WS_DINT;
  float* ctx    = ws + WS_CTX;
  float* hnew   = ws + WS_HNEW;
  float* ga0    = ws + WS_GA0;
  float* ga1    = ws + WS_GA1;
  float* gb0    = ws + WS_GB0;
  float* gb1    = ws + WS_GB1;
  float* pgen   = ws + WS_PGEN;
  unsigned short* abf = (unsigned short*)(ws + WS_ABF);
  float* part   = ws + WS_PART;

  k_prep<<<203, 256, 0, stream>>>(x, emb, h0, dinT);
  k_score<<<6400, 256, 0, stream>>>(enc, h0, Vw, Vb, score);
  k_ctx<<<512, 256, 0, stream>>>(enc, score, wbuf, part);
  k_ctx_reduce<<<64, 256, 0, stream>>>(part, ctx, dinT);
  k_gates<<<512, 256, 0, stream>>>(Wih, Whh, dinT, ga0, ga1, gb0, gb1);
  k_lstm<<<128, 256, 0, stream>>>(c0, bih, bhh, ga0, ga1, gb0, gb1, ctx, hnew, abf, out);
  k_pgen<<<64, 256, 0, stream>>>(genw, genb, ctx, hnew, dinT, pgen);
  k_gemm<<<3125, 256, 0, stream>>>(outw, outb, abf, pgen, out);
  k_scatter<<<100, 256, 0, stream>>>(text, wbuf, pgen, out);
}

// Round 4
// 165.141 us; speedup vs baseline: 1.2865x; 1.2865x over previous
//
#include <hip/hip_runtime.h>
#include <hip/hip_bf16.h>

#define BB 64
#define SS 400
#define HH 512
#define EE 300
#define VV 50000
#define KD 812     // E+H (LSTM input width)
#define KG 1324    // 2H+E (gen_in width)
#define KC 1024    // 2H (out_cat width)
#define BV (BB*VV)

typedef __attribute__((ext_vector_type(8))) short bf16x8;
typedef __attribute__((ext_vector_type(4))) float f32x4;

// ---- workspace layout (float offsets) ----
#define WS_SCORE 0          // [B*S]
#define WS_W     25600      // [B*S]
#define WS_CTX   51200      // [64][512]
#define WS_HNEW  83968      // [64][512]
#define WS_G0    116736     // [2048][64] f32 gate partials x4
#define WS_G1    247808
#define WS_G2    378880
#define WS_G3    509952
#define WS_PGEN  641024     // [64]
#define WS_PART  641088     // [64][8][512] ctx partials
#define WS_ABF   903232     // ushort [64][1024] bf16 out_cat
#define WS_AD1   936000     // ushort [64][832]  bf16 [xe|ctx|0pad]
#define WS_AD2   962624     // ushort [64][512]  bf16 h_prev

__device__ __forceinline__ float sigm(float x){ return 1.f/(1.f+__expf(-x)); }
__device__ __forceinline__ float ftanh(float x){
  x = fminf(fmaxf(x,-15.f),15.f);
  float e = __expf(2.f*x);
  return (e-1.f)/(e+1.f);
}
__device__ __forceinline__ unsigned short f2bf(float f){
  unsigned int u = __builtin_bit_cast(unsigned int, f);
  u += 0x7fffu + ((u>>16)&1u);
  return (unsigned short)(u>>16);
}

// Register-pipelined MFMA segment: depth-3 ring, loads issued D steps ahead,
// all ring indices static under full unroll (no scratch). B=f32 weights
// (converted in-reg via cvt_pk), A=bf16 activations (4 M-tiles).
template<int NSTEP>
__device__ __forceinline__ void mfma_seg(const float* __restrict__ wr,
    const unsigned short* __restrict__ a0, const unsigned short* __restrict__ a1,
    const unsigned short* __restrict__ a2, const unsigned short* __restrict__ a3,
    f32x4& acc0, f32x4& acc1, f32x4& acc2, f32x4& acc3)
{
  constexpr int D = NSTEP >= 3 ? 3 : NSTEP;
  float4 wb[D][2];
  bf16x8 ab[D][4];
  #pragma unroll
  for (int p=0; p<D; ++p){
    wb[p][0] = *(const float4*)(wr + p*32);
    wb[p][1] = *(const float4*)(wr + p*32 + 4);
    ab[p][0] = *(const bf16x8*)(a0 + p*32);
    ab[p][1] = *(const bf16x8*)(a1 + p*32);
    ab[p][2] = *(const bf16x8*)(a2 + p*32);
    ab[p][3] = *(const bf16x8*)(a3 + p*32);
  }
  #pragma unroll
  for (int ks=0; ks<NSTEP; ++ks){
    const int cur = ks % D;
    float4 f0 = wb[cur][0], f1 = wb[cur][1];
    bf16x8 A0 = ab[cur][0], A1 = ab[cur][1], A2 = ab[cur][2], A3 = ab[cur][3];
    if (ks + D < NSTEP){
      wb[cur][0] = *(const float4*)(wr + (ks+D)*32);
      wb[cur][1] = *(const float4*)(wr + (ks+D)*32 + 4);
      ab[cur][0] = *(const bf16x8*)(a0 + (ks+D)*32);
      ab[cur][1] = *(const bf16x8*)(a1 + (ks+D)*32);
      ab[cur][2] = *(const bf16x8*)(a2 + (ks+D)*32);
      ab[cur][3] = *(const bf16x8*)(a3 + (ks+D)*32);
    }
    union { bf16x8 v; unsigned int u[4]; } bb;
    asm("v_cvt_pk_bf16_f32 %0, %1, %2" : "=v"(bb.u[0]) : "v"(f0.x), "v"(f0.y));
    asm("v_cvt_pk_bf16_f32 %0, %1, %2" : "=v"(bb.u[1]) : "v"(f0.z), "v"(f0.w));
    asm("v_cvt_pk_bf16_f32 %0, %1, %2" : "=v"(bb.u[2]) : "v"(f1.x), "v"(f1.y));
    asm("v_cvt_pk_bf16_f32 %0, %1, %2" : "=v"(bb.u[3]) : "v"(f1.z), "v"(f1.w));
    acc0 = __builtin_amdgcn_mfma_f32_16x16x32_bf16(A0, bb.v, acc0, 0,0,0);
    acc1 = __builtin_amdgcn_mfma_f32_16x16x32_bf16(A1, bb.v, acc1, 0,0,0);
    acc2 = __builtin_amdgcn_mfma_f32_16x16x32_bf16(A2, bb.v, acc2, 0,0,0);
    acc3 = __builtin_amdgcn_mfma_f32_16x16x32_bf16(A3, bb.v, acc3, 0,0,0);
  }
}

// K0: build bf16 activation buffers: ad1 = [xe(300) | ctx(later) | 0-pad(20)], ad2 = h_prev
__global__ __launch_bounds__(256) void k_prep(const int* __restrict__ x,
    const float* __restrict__ emb, const float* __restrict__ h0,
    unsigned short* __restrict__ ad1, unsigned short* __restrict__ ad2)
{
  int n = blockIdx.x*256 + threadIdx.x;     // 336 blocks: 53248 + 32768
  if (n < BB*832){
    int b = n/832, k = n - b*832;
    if (k < EE) ad1[n] = f2bf(emb[(size_t)x[b]*EE + k]);
    else if (k >= 812) ad1[n] = 0;
  } else {
    int m = n - BB*832;
    ad2[m] = f2bf(h0[m]);
  }
}

// K1: score[b,s] = V_w . tanh(enc[b,s,:] + h_prev[b,:]) + V_b
__global__ __launch_bounds__(256) void k_score(const float* __restrict__ enc,
    const float* __restrict__ h0, const float* __restrict__ Vw,
    const float* __restrict__ Vb, float* __restrict__ score)
{
  int wv = threadIdx.x >> 6, lane = threadIdx.x & 63;
  int pair = blockIdx.x*4 + wv;
  int b = pair / SS;
  int i0 = lane*8;
  const float4* ep = (const float4*)(enc + (size_t)pair*HH + i0);
  const float4* hp = (const float4*)(h0 + b*HH + i0);
  const float4* vp = (const float4*)(Vw + i0);
  float4 e0 = ep[0], e1 = ep[1];
  float4 hv0 = hp[0], hv1 = hp[1];
  float4 v0 = vp[0], v1 = vp[1];
  float sum = ftanh(e0.x+hv0.x)*v0.x + ftanh(e0.y+hv0.y)*v0.y
            + ftanh(e0.z+hv0.z)*v0.z + ftanh(e0.w+hv0.w)*v0.w
            + ftanh(e1.x+hv1.x)*v1.x + ftanh(e1.y+hv1.y)*v1.y
            + ftanh(e1.z+hv1.z)*v1.z + ftanh(e1.w+hv1.w)*v1.w;
  #pragma unroll
  for (int off=32; off; off>>=1) sum += __shfl_xor(sum, off);
  if (lane==0) score[pair] = sum + Vb[0];
}

// K2: per (b, s-chunk): recompute softmax over full row, partial ctx over 50 s.
__global__ __launch_bounds__(256) void k_ctx(const float* __restrict__ enc,
    const float* __restrict__ score, float* __restrict__ wout,
    float* __restrict__ part)
{
  __shared__ float red[256];
  __shared__ float wl[SS];
  int b = blockIdx.x >> 3, sp = blockIdx.x & 7;
  int t = threadIdx.x;
  float v1 = score[b*SS + t];
  float v2 = (t < SS-256) ? score[b*SS + t + 256] : -1e30f;
  red[t] = fmaxf(v1, v2);
  __syncthreads();
  for (int o=128; o; o>>=1){ if (t<o) red[t] = fmaxf(red[t], red[t+o]); __syncthreads(); }
  float mx = red[0];
  __syncthreads();
  float e1 = __expf(v1 - mx);
  float e2 = (t < SS-256) ? __expf(v2 - mx) : 0.f;
  red[t] = e1 + e2;
  __syncthreads();
  for (int o=128; o; o>>=1){ if (t<o) red[t] += red[t+o]; __syncthreads(); }
  float inv = 1.f/red[0];
  float w1 = e1*inv;
  wl[t] = w1;
  if (sp==0) wout[b*SS + t] = w1;
  if (t < SS-256){
    float w2 = e2*inv;
    wl[t+256] = w2;
    if (sp==0) wout[b*SS + t + 256] = w2;
  }
  __syncthreads();
  float a0 = 0.f, a1 = 0.f;
  const float* ebase = enc + ((size_t)b*SS + sp*50)*HH + 2*t;
  #pragma unroll 5
  for (int s=0; s<50; ++s){
    float wg = wl[sp*50 + s];
    float2 e = *(const float2*)(ebase + s*HH);
    a0 += wg * e.x;
    a1 += wg * e.y;
  }
  *(float2*)(part + (size_t)(b*8+sp)*HH + 2*t) = make_float2(a0, a1);
}

// K3: reduce 8 ctx partials -> ctx f32 + ad1 ctx slice (bf16)
__global__ __launch_bounds__(256) void k_ctx_reduce(const float* __restrict__ part,
    float* __restrict__ ctx, unsigned short* __restrict__ ad1)
{
  int b = blockIdx.x, t = threadIdx.x;
  float a0=0.f, a1=0.f;
  #pragma unroll
  for (int sp=0; sp<8; ++sp){
    float2 e = *(const float2*)(part + (size_t)(b*8+sp)*HH + 2*t);
    a0 += e.x; a1 += e.y;
  }
  *(float2*)(ctx + b*HH + 2*t) = make_float2(a0, a1);
  ad1[b*832 + EE + 2*t]     = f2bf(a0);
  ad1[b*832 + EE + 2*t + 1] = f2bf(a1);
}

// K4: gates via MFMA. 512 wave-tiles = 128 j-tiles x 4 K-parts.
// part0/1: Wih with ad1 (k [0,416)/[416,832), zero-padded tail); part2/3: Whh with ad2.
__global__ __launch_bounds__(128, 4) void k_gates(const float* __restrict__ Wih,
    const float* __restrict__ Whh, const unsigned short* __restrict__ ad1,
    const unsigned short* __restrict__ ad2,
    float* __restrict__ g0, float* __restrict__ g1,
    float* __restrict__ g2, float* __restrict__ g3)
{
  int wt = blockIdx.x*2 + (threadIdx.x >> 6);   // 0..511
  int lane = threadIdx.x & 63;
  int col = lane & 15, kg = lane >> 4;
  int jt = wt >> 2, part = wt & 3;
  int j = jt*16 + col;
  f32x4 acc0={0.f,0.f,0.f,0.f}, acc1=acc0, acc2=acc0, acc3=acc0;
  float* g;
  if (part < 2){
    int k0 = part ? 416 : 0;
    const float* wr = Wih + (size_t)j*KD + k0 + kg*8;
    const unsigned short* a = ad1 + col*832 + k0 + kg*8;
    mfma_seg<13>(wr, a, a+16*832, a+32*832, a+48*832, acc0,acc1,acc2,acc3);
    g = part ? g1 : g0;
  } else {
    int k0 = (part==3) ? 256 : 0;
    const float* wr = Whh + (size_t)j*HH + k0 + kg*8;
    const unsigned short* a = ad2 + col*512 + k0 + kg*8;
    mfma_seg<8>(wr, a, a+16*512, a+32*512, a+48*512, acc0,acc1,acc2,acc3);
    g = (part==3) ? g3 : g2;
  }
  #pragma unroll
  for (int i=0;i<4;i++){
    g[(size_t)j*BB + 0*16 + kg*4 + i] = acc0[i];
    g[(size_t)j*BB + 1*16 + kg*4 + i] = acc1[i];
    g[(size_t)j*BB + 2*16 + kg*4 + i] = acc2[i];
    g[(size_t)j*BB + 3*16 + kg*4 + i] = acc3[i];
  }
}

// K5: LSTM cell elementwise
__global__ __launch_bounds__(256) void k_lstm(const float* __restrict__ c0,
    const float* __restrict__ bih, const float* __restrict__ bhh,
    const float* __restrict__ g0, const float* __restrict__ g1,
    const float* __restrict__ g2, const float* __restrict__ g3,
    const float* __restrict__ ctx, float* __restrict__ hnew,
    unsigned short* __restrict__ abf, float* __restrict__ out)
{
  int n = blockIdx.x*256 + threadIdx.x;   // < 32768
  int b = n & 63, h = n >> 6;
  #define GSUM(off) (g0[(off)*BB+b] + g1[(off)*BB+b] + g2[(off)*BB+b] + g3[(off)*BB+b] + bih[off] + bhh[off])
  float gi = GSUM(h);
  float gf = GSUM(HH+h);
  float gg = GSUM(2*HH+h);
  float go = GSUM(3*HH+h);
  #undef GSUM
  float cn = sigm(gf)*c0[b*HH+h] + sigm(gi)*ftanh(gg);
  float hn = sigm(go)*ftanh(cn);
  out[BV + b*HH + h]          = hn;
  out[BV + BB*HH + b*HH + h]  = cn;
  hnew[b*HH + h] = hn;
  abf[b*KC + h]      = f2bf(hn);
  abf[b*KC + HH + h] = f2bf(ctx[b*HH + h]);
}

// K6: p_gen[b] = sigmoid(gen_w . [ctx, h_new, xe] + gen_b)
__global__ __launch_bounds__(256) void k_pgen(const float* __restrict__ genw,
    const float* __restrict__ genb, const float* __restrict__ ctx,
    const float* __restrict__ hnew, const int* __restrict__ x,
    const float* __restrict__ emb, float* __restrict__ pgen)
{
  __shared__ float red[256];
  int b = blockIdx.x, t = threadIdx.x;
  float p = 0.f;
  for (int k=t; k<KG; k+=256){
    float g = genw[k];
    float v = (k < HH) ? ctx[b*HH + k]
            : (k < 2*HH) ? hnew[b*HH + k - HH]
            : emb[(size_t)x[b]*EE + (k - 2*HH)];
    p += g*v;
  }
  red[t] = p; __syncthreads();
  for (int o=128; o; o>>=1){ if (t<o) red[t] += red[t+o]; __syncthreads(); }
  if (t==0) pgen[b] = sigm(red[0] + genb[0]);
}

// K7: out[b,v] = pgen[b]*(out_cat . out_w[v,:] + out_b[v]).
// Register-pipelined: wave owns 16 v-cols x all 64 batches; 32 K-steps, depth-3 ring.
__global__ __launch_bounds__(128, 4) void k_gemm(const float* __restrict__ out_w,
    const float* __restrict__ out_b, const unsigned short* __restrict__ abf,
    const float* __restrict__ pgen, float* __restrict__ out)
{
  int wt = blockIdx.x*2 + (threadIdx.x >> 6);
  if (wt >= VV/16) return;
  int lane = threadIdx.x & 63;
  int col = lane & 15, kg = lane >> 4;
  int v = wt*16 + col;
  const float* wr = out_w + (size_t)v*KC + kg*8;
  const unsigned short* a = abf + col*KC + kg*8;
  f32x4 acc0={0.f,0.f,0.f,0.f}, acc1=acc0, acc2=acc0, acc3=acc0;
  mfma_seg<32>(wr, a, a+16*KC, a+32*KC, a+48*KC, acc0,acc1,acc2,acc3);
  float ob = out_b[v];
  #pragma unroll
  for (int i=0;i<4;i++){
    int b0 = 0*16 + kg*4 + i;
    int b1 = 1*16 + kg*4 + i;
    int b2 = 2*16 + kg*4 + i;
    int b3 = 3*16 + kg*4 + i;
    out[(size_t)b0*VV + v] = pgen[b0]*(acc0[i] + ob);
    out[(size_t)b1*VV + v] = pgen[b1]*(acc1[i] + ob);
    out[(size_t)b2*VV + v] = pgen[b2]*(acc2[i] + ob);
    out[(size_t)b3*VV + v] = pgen[b3]*(acc3[i] + ob);
  }
}

// K8: pointer scatter, last-duplicate-wins; text row staged in LDS, branch-free scan.
__global__ __launch_bounds__(256) void k_scatter(const int* __restrict__ text,
    const float* __restrict__ w, const float* __restrict__ pgen,
    float* __restrict__ out)
{
  __shared__ int ts[SS];
  int b = blockIdx.x, t = threadIdx.x;
  ts[t] = text[b*SS + t];
  if (t + 256 < SS) ts[t+256] = text[b*SS + t + 256];
  __syncthreads();
  float pp = 1.f - pgen[b];
  #pragma unroll
  for (int rep=0; rep<2; ++rep){
    int s = t + rep*256;
    if (s < SS){
      int v = ts[s];
      bool dup = false;
      #pragma unroll 4
      for (int s2=s+1; s2<SS; ++s2) dup = dup || (ts[s2]==v);
      if (!dup) out[(size_t)b*VV + v] += pp * w[b*SS + s];
    }
  }
}

extern "C" void kernel_launch(void* const* d_in, const int* in_sizes, int n_in,
                              void* d_out, int out_size, void* d_ws, size_t ws_size,
                              hipStream_t stream)
{
  const int*   x    = (const int*)  d_in[0];
  const float* enc  = (const float*)d_in[1];
  const float* h0   = (const float*)d_in[2];
  const float* c0   = (const float*)d_in[3];
  const int*   text = (const int*)  d_in[4];
  const float* emb  = (const float*)d_in[6];
  const float* Vw   = (const float*)d_in[7];
  const float* Vb   = (const float*)d_in[8];
  const float* genw = (const float*)d_in[9];
  const float* genb = (const float*)d_in[10];
  const float* outw = (const float*)d_in[11];
  const float* outb = (const float*)d_in[12];
  const float* Wih  = (const float*)d_in[13];
  const float* Whh  = (const float*)d_in[14];
  const float* bih  = (const float*)d_in[15];
  const float* bhh  = (const float*)d_in[16];
  float* out = (float*)d_out;

  float* ws     = (float*)d_ws;
  float* score  = ws + WS_SCORE;
  float* wbuf   = ws + WS_W;
  float* ctx    = ws + WS_CTX;
  float* hnew   = ws + WS_HNEW;
  float* g0     = ws + WS_G0;
  float* g1     = ws + WS_G1;
  float* g2     = ws + WS_G2;
  float* g3     = ws + WS_G3;
  float* pgen   = ws + WS_PGEN;
  float* part   = ws + WS_PART;
  unsigned short* abf = (unsigned short*)(ws + WS_ABF);
  unsigned short* ad1 = (unsigned short*)(ws + WS_AD1);
  unsigned short* ad2 = (unsigned short*)(ws + WS_AD2);

  k_prep<<<336, 256, 0, stream>>>(x, emb, h0, ad1, ad2);
  k_score<<<6400, 256, 0, stream>>>(enc, h0, Vw, Vb, score);
  k_ctx<<<512, 256, 0, stream>>>(enc, score, wbuf, part);
  k_ctx_reduce<<<64, 256, 0, stream>>>(part, ctx, ad1);
  k_gates<<<256, 128, 0, stream>>>(Wih, Whh, ad1, ad2, g0, g1, g2, g3);
  k_lstm<<<128, 256, 0, stream>>>(c0, bih, bhh, g0, g1, g2, g3, ctx, hnew, abf, out);
  k_pgen<<<64, 256, 0, stream>>>(genw, genb, ctx, hnew, x, emb, pgen);
  k_gemm<<<1563, 128, 0, stream>>>(outw, outb, abf, pgen, out);
  k_scatter<<<64, 256, 0, stream>>>(text, wbuf, pgen, out);
}

// Round 6
// 163.942 us; speedup vs baseline: 1.2959x; 1.0073x over previous
//
#include <hip/hip_runtime.h>
#include <hip/hip_bf16.h>

#define BB 64
#define SS 400
#define HH 512
#define EE 300
#define VV 50000
#define KD 812     // E+H (LSTM input width)
#define KG 1324    // 2H+E (gen_in width)
#define KC 1024    // 2H (out_cat width)
#define BV (BB*VV)

typedef __attribute__((ext_vector_type(8))) short bf16x8;
typedef __attribute__((ext_vector_type(4))) float f32x4;

// ---- workspace layout (float offsets) ----
#define WS_SCORE 0          // [B*S]
#define WS_W     25600      // [B*S]
#define WS_CTX   51200      // [64][512]
#define WS_HNEW  83968      // [64][512]
#define WS_G0    116736     // [2048][64] f32 gate partials x4
#define WS_G1    247808
#define WS_G2    378880
#define WS_G3    509952
#define WS_PGEN  641024     // [64]
#define WS_PART  641088     // [64][8][512] ctx partials
#define WS_ABF   903232     // ushort [64][1024] bf16 out_cat
#define WS_AD1   936000     // ushort [64][832]  bf16 [xe|ctx|0pad]
#define WS_AD2   962624     // ushort [64][512]  bf16 h_prev

__device__ __forceinline__ float sigm(float x){ return 1.f/(1.f+__expf(-x)); }
__device__ __forceinline__ float ftanh(float x){
  x = fminf(fmaxf(x,-15.f),15.f);
  float e = __expf(2.f*x);
  return (e-1.f)/(e+1.f);
}
__device__ __forceinline__ unsigned short f2bf(float f){
  unsigned int u = __builtin_bit_cast(unsigned int, f);
  u += 0x7fffu + ((u>>16)&1u);
  return (unsigned short)(u>>16);
}

// ---- software-pipelined MFMA segment, NAMED ping-pong register sets ----
// No arrays -> no runtime indexing -> no scratch, regardless of unrolling.
// NOTE: never paste a macro token directly against ".x" (pp-number trap):
// copy w##S##0 into a local first.
#define LDW(S, off) { w##S##0 = *(const float4*)(wr + (off)*32); \
                      w##S##1 = *(const float4*)(wr + (off)*32 + 4); }
#define LDA(S, off) { a##S##0 = *(const bf16x8*)(a0 + (off)*32); \
                      a##S##1 = *(const bf16x8*)(a1 + (off)*32); \
                      a##S##2 = *(const bf16x8*)(a2 + (off)*32); \
                      a##S##3 = *(const bf16x8*)(a3 + (off)*32); }
#define CONS(S) { union { bf16x8 v; unsigned int u[4]; } bb_; \
  float4 f0_ = w##S##0; float4 f1_ = w##S##1; \
  asm("v_cvt_pk_bf16_f32 %0, %1, %2" : "=v"(bb_.u[0]) : "v"(f0_.x), "v"(f0_.y)); \
  asm("v_cvt_pk_bf16_f32 %0, %1, %2" : "=v"(bb_.u[1]) : "v"(f0_.z), "v"(f0_.w)); \
  asm("v_cvt_pk_bf16_f32 %0, %1, %2" : "=v"(bb_.u[2]) : "v"(f1_.x), "v"(f1_.y)); \
  asm("v_cvt_pk_bf16_f32 %0, %1, %2" : "=v"(bb_.u[3]) : "v"(f1_.z), "v"(f1_.w)); \
  acc0 = __builtin_amdgcn_mfma_f32_16x16x32_bf16(a##S##0, bb_.v, acc0, 0,0,0); \
  acc1 = __builtin_amdgcn_mfma_f32_16x16x32_bf16(a##S##1, bb_.v, acc1, 0,0,0); \
  acc2 = __builtin_amdgcn_mfma_f32_16x16x32_bf16(a##S##2, bb_.v, acc2, 0,0,0); \
  acc3 = __builtin_amdgcn_mfma_f32_16x16x32_bf16(a##S##3, bb_.v, acc3, 0,0,0); }

// depth-4 pipeline, NSTEP % 4 == 0
template<int NSTEP>
__device__ __forceinline__ void mfma_seg4(const float* __restrict__ wr,
    const unsigned short* __restrict__ a0, const unsigned short* __restrict__ a1,
    const unsigned short* __restrict__ a2, const unsigned short* __restrict__ a3,
    f32x4& acc0, f32x4& acc1, f32x4& acc2, f32x4& acc3)
{
  static_assert(NSTEP % 4 == 0 && NSTEP >= 8, "");
  float4 wA0,wA1, wB0,wB1, wC0,wC1, wD0,wD1;
  bf16x8 aA0,aA1,aA2,aA3, aB0,aB1,aB2,aB3, aC0,aC1,aC2,aC3, aD0,aD1,aD2,aD3;
  LDW(A,0) LDA(A,0)
  LDW(B,1) LDA(B,1)
  LDW(C,2) LDA(C,2)
  LDW(D,3) LDA(D,3)
  #pragma unroll
  for (int ks=0; ks<NSTEP; ks+=4){
    CONS(A) if (ks+4 < NSTEP){ LDW(A,ks+4) LDA(A,ks+4) }
    CONS(B) if (ks+5 < NSTEP){ LDW(B,ks+5) LDA(B,ks+5) }
    CONS(C) if (ks+6 < NSTEP){ LDW(C,ks+6) LDA(C,ks+6) }
    CONS(D) if (ks+7 < NSTEP){ LDW(D,ks+7) LDA(D,ks+7) }
  }
}

// depth-2 pipeline, NSTEP % 2 == 0
template<int NSTEP>
__device__ __forceinline__ void mfma_seg2(const float* __restrict__ wr,
    const unsigned short* __restrict__ a0, const unsigned short* __restrict__ a1,
    const unsigned short* __restrict__ a2, const unsigned short* __restrict__ a3,
    f32x4& acc0, f32x4& acc1, f32x4& acc2, f32x4& acc3)
{
  static_assert(NSTEP % 2 == 0 && NSTEP >= 4, "");
  float4 wA0,wA1, wB0,wB1;
  bf16x8 aA0,aA1,aA2,aA3, aB0,aB1,aB2,aB3;
  LDW(A,0) LDA(A,0)
  LDW(B,1) LDA(B,1)
  #pragma unroll
  for (int ks=0; ks<NSTEP; ks+=2){
    CONS(A) if (ks+2 < NSTEP){ LDW(A,ks+2) LDA(A,ks+2) }
    CONS(B) if (ks+3 < NSTEP){ LDW(B,ks+3) LDA(B,ks+3) }
  }
}

// K0: build bf16 activation buffers: ad1 = [xe(300) | ctx(later) | 0-pad(20)], ad2 = h_prev
__global__ __launch_bounds__(256) void k_prep(const int* __restrict__ x,
    const float* __restrict__ emb, const float* __restrict__ h0,
    unsigned short* __restrict__ ad1, unsigned short* __restrict__ ad2)
{
  int n = blockIdx.x*256 + threadIdx.x;     // 336 blocks: 53248 + 32768
  if (n < BB*832){
    int b = n/832, k = n - b*832;
    if (k < EE) ad1[n] = f2bf(emb[(size_t)x[b]*EE + k]);
    else if (k >= 812) ad1[n] = 0;
  } else {
    int m = n - BB*832;
    ad2[m] = f2bf(h0[m]);
  }
}

// K1: score[b,s] = V_w . tanh(enc[b,s,:] + h_prev[b,:]) + V_b
__global__ __launch_bounds__(256) void k_score(const float* __restrict__ enc,
    const float* __restrict__ h0, const float* __restrict__ Vw,
    const float* __restrict__ Vb, float* __restrict__ score)
{
  int wv = threadIdx.x >> 6, lane = threadIdx.x & 63;
  int pair = blockIdx.x*4 + wv;
  int b = pair / SS;
  int i0 = lane*8;
  const float4* ep = (const float4*)(enc + (size_t)pair*HH + i0);
  const float4* hp = (const float4*)(h0 + b*HH + i0);
  const float4* vp = (const float4*)(Vw + i0);
  float4 e0 = ep[0], e1 = ep[1];
  float4 hv0 = hp[0], hv1 = hp[1];
  float4 v0 = vp[0], v1 = vp[1];
  float sum = ftanh(e0.x+hv0.x)*v0.x + ftanh(e0.y+hv0.y)*v0.y
            + ftanh(e0.z+hv0.z)*v0.z + ftanh(e0.w+hv0.w)*v0.w
            + ftanh(e1.x+hv1.x)*v1.x + ftanh(e1.y+hv1.y)*v1.y
            + ftanh(e1.z+hv1.z)*v1.z + ftanh(e1.w+hv1.w)*v1.w;
  #pragma unroll
  for (int off=32; off; off>>=1) sum += __shfl_xor(sum, off);
  if (lane==0) score[pair] = sum + Vb[0];
}

// K2: per (b, s-chunk): recompute softmax over full row, partial ctx over 50 s.
__global__ __launch_bounds__(256) void k_ctx(const float* __restrict__ enc,
    const float* __restrict__ score, float* __restrict__ wout,
    float* __restrict__ part)
{
  __shared__ float red[256];
  __shared__ float wl[SS];
  int b = blockIdx.x >> 3, sp = blockIdx.x & 7;
  int t = threadIdx.x;
  float v1 = score[b*SS + t];
  float v2 = (t < SS-256) ? score[b*SS + t + 256] : -1e30f;
  red[t] = fmaxf(v1, v2);
  __syncthreads();
  for (int o=128; o; o>>=1){ if (t<o) red[t] = fmaxf(red[t], red[t+o]); __syncthreads(); }
  float mx = red[0];
  __syncthreads();
  float e1 = __expf(v1 - mx);
  float e2 = (t < SS-256) ? __expf(v2 - mx) : 0.f;
  red[t] = e1 + e2;
  __syncthreads();
  for (int o=128; o; o>>=1){ if (t<o) red[t] += red[t+o]; __syncthreads(); }
  float inv = 1.f/red[0];
  float w1 = e1*inv;
  wl[t] = w1;
  if (sp==0) wout[b*SS + t] = w1;
  if (t < SS-256){
    float w2 = e2*inv;
    wl[t+256] = w2;
    if (sp==0) wout[b*SS + t + 256] = w2;
  }
  __syncthreads();
  float a0 = 0.f, a1 = 0.f;
  const float* ebase = enc + ((size_t)b*SS + sp*50)*HH + 2*t;
  #pragma unroll 5
  for (int s=0; s<50; ++s){
    float wg = wl[sp*50 + s];
    float2 e = *(const float2*)(ebase + s*HH);
    a0 += wg * e.x;
    a1 += wg * e.y;
  }
  *(float2*)(part + (size_t)(b*8+sp)*HH + 2*t) = make_float2(a0, a1);
}

// K3: reduce 8 ctx partials -> ctx f32 + ad1 ctx slice (bf16)
__global__ __launch_bounds__(256) void k_ctx_reduce(const float* __restrict__ part,
    float* __restrict__ ctx, unsigned short* __restrict__ ad1)
{
  int b = blockIdx.x, t = threadIdx.x;
  float a0=0.f, a1=0.f;
  #pragma unroll
  for (int sp=0; sp<8; ++sp){
    float2 e = *(const float2*)(part + (size_t)(b*8+sp)*HH + 2*t);
    a0 += e.x; a1 += e.y;
  }
  *(float2*)(ctx + b*HH + 2*t) = make_float2(a0, a1);
  ad1[b*832 + EE + 2*t]     = f2bf(a0);
  ad1[b*832 + EE + 2*t + 1] = f2bf(a1);
}

// K4: gates via MFMA. 512 wave-tiles = 128 j-tiles x 4 K-parts (12/14/8/8 steps).
__global__ __launch_bounds__(128, 4) void k_gates(const float* __restrict__ Wih,
    const float* __restrict__ Whh, const unsigned short* __restrict__ ad1,
    const unsigned short* __restrict__ ad2,
    float* __restrict__ g0, float* __restrict__ g1,
    float* __restrict__ g2, float* __restrict__ g3)
{
  int wt = blockIdx.x*2 + (threadIdx.x >> 6);   // 0..511
  int lane = threadIdx.x & 63;
  int col = lane & 15, kg = lane >> 4;
  int jt = wt >> 2, part = wt & 3;
  int j = jt*16 + col;
  f32x4 acc0={0.f,0.f,0.f,0.f}, acc1=acc0, acc2=acc0, acc3=acc0;
  float* g;
  if (part < 2){
    int k0 = part ? 384 : 0;
    const float* wr = Wih + (size_t)j*KD + k0 + kg*8;
    const unsigned short* a = ad1 + col*832 + k0 + kg*8;
    if (part) mfma_seg2<14>(wr, a, a+16*832, a+32*832, a+48*832, acc0,acc1,acc2,acc3);
    else      mfma_seg2<12>(wr, a, a+16*832, a+32*832, a+48*832, acc0,acc1,acc2,acc3);
    g = part ? g1 : g0;
  } else {
    int k0 = (part==3) ? 256 : 0;
    const float* wr = Whh + (size_t)j*HH + k0 + kg*8;
    const unsigned short* a = ad2 + col*512 + k0 + kg*8;
    mfma_seg2<8>(wr, a, a+16*512, a+32*512, a+48*512, acc0,acc1,acc2,acc3);
    g = (part==3) ? g3 : g2;
  }
  #pragma unroll
  for (int i=0;i<4;i++){
    g[(size_t)j*BB + 0*16 + kg*4 + i] = acc0[i];
    g[(size_t)j*BB + 1*16 + kg*4 + i] = acc1[i];
    g[(size_t)j*BB + 2*16 + kg*4 + i] = acc2[i];
    g[(size_t)j*BB + 3*16 + kg*4 + i] = acc3[i];
  }
}

// K5: LSTM cell elementwise
__global__ __launch_bounds__(256) void k_lstm(const float* __restrict__ c0,
    const float* __restrict__ bih, const float* __restrict__ bhh,
    const float* __restrict__ g0, const float* __restrict__ g1,
    const float* __restrict__ g2, const float* __restrict__ g3,
    const float* __restrict__ ctx, float* __restrict__ hnew,
    unsigned short* __restrict__ abf, float* __restrict__ out)
{
  int n = blockIdx.x*256 + threadIdx.x;   // < 32768
  int b = n & 63, h = n >> 6;
  #define GSUM(off) (g0[(off)*BB+b] + g1[(off)*BB+b] + g2[(off)*BB+b] + g3[(off)*BB+b] + bih[off] + bhh[off])
  float gi = GSUM(h);
  float gf = GSUM(HH+h);
  float gg = GSUM(2*HH+h);
  float go = GSUM(3*HH+h);
  #undef GSUM
  float cn = sigm(gf)*c0[b*HH+h] + sigm(gi)*ftanh(gg);
  float hn = sigm(go)*ftanh(cn);
  out[BV + b*HH + h]          = hn;
  out[BV + BB*HH + b*HH + h]  = cn;
  hnew[b*HH + h] = hn;
  abf[b*KC + h]      = f2bf(hn);
  abf[b*KC + HH + h] = f2bf(ctx[b*HH + h]);
}

// K6: p_gen[b] = sigmoid(gen_w . [ctx, h_new, xe] + gen_b)
__global__ __launch_bounds__(256) void k_pgen(const float* __restrict__ genw,
    const float* __restrict__ genb, const float* __restrict__ ctx,
    const float* __restrict__ hnew, const int* __restrict__ x,
    const float* __restrict__ emb, float* __restrict__ pgen)
{
  __shared__ float red[256];
  int b = blockIdx.x, t = threadIdx.x;
  float p = 0.f;
  for (int k=t; k<KG; k+=256){
    float g = genw[k];
    float v = (k < HH) ? ctx[b*HH + k]
            : (k < 2*HH) ? hnew[b*HH + k - HH]
            : emb[(size_t)x[b]*EE + (k - 2*HH)];
    p += g*v;
  }
  red[t] = p; __syncthreads();
  for (int o=128; o; o>>=1){ if (t<o) red[t] += red[t+o]; __syncthreads(); }
  if (t==0) pgen[b] = sigm(red[0] + genb[0]);
}

// K7: out[b,v] = pgen[b]*(out_cat . out_w[v,:] + out_b[v]).
// Register-pipelined depth-4: wave owns 16 v-cols x all 64 batches; 32 K-steps.
__global__ __launch_bounds__(128, 3) void k_gemm(const float* __restrict__ out_w,
    const float* __restrict__ out_b, const unsigned short* __restrict__ abf,
    const float* __restrict__ pgen, float* __restrict__ out)
{
  int wt = blockIdx.x*2 + (threadIdx.x >> 6);
  if (wt >= VV/16) return;
  int lane = threadIdx.x & 63;
  int col = lane & 15, kg = lane >> 4;
  int v = wt*16 + col;
  const float* wr = out_w + (size_t)v*KC + kg*8;
  const unsigned short* a = abf + col*KC + kg*8;
  f32x4 acc0={0.f,0.f,0.f,0.f}, acc1=acc0, acc2=acc0, acc3=acc0;
  mfma_seg4<32>(wr, a, a+16*KC, a+32*KC, a+48*KC, acc0,acc1,acc2,acc3);
  float ob = out_b[v];
  #pragma unroll
  for (int i=0;i<4;i++){
    int b0 = 0*16 + kg*4 + i;
    int b1 = 1*16 + kg*4 + i;
    int b2 = 2*16 + kg*4 + i;
    int b3 = 3*16 + kg*4 + i;
    out[(size_t)b0*VV + v] = pgen[b0]*(acc0[i] + ob);
    out[(size_t)b1*VV + v] = pgen[b1]*(acc1[i] + ob);
    out[(size_t)b2*VV + v] = pgen[b2]*(acc2[i] + ob);
    out[(size_t)b3*VV + v] = pgen[b3]*(acc3[i] + ob);
  }
}

// K8: pointer scatter, last-duplicate-wins; text row staged in LDS, branch-free scan.
__global__ __launch_bounds__(256) void k_scatter(const int* __restrict__ text,
    const float* __restrict__ w, const float* __restrict__ pgen,
    float* __restrict__ out)
{
  __shared__ int ts[SS];
  int b = blockIdx.x, t = threadIdx.x;
  ts[t] = text[b*SS + t];
  if (t + 256 < SS) ts[t+256] = text[b*SS + t + 256];
  __syncthreads();
  float pp = 1.f - pgen[b];
  #pragma unroll
  for (int rep=0; rep<2; ++rep){
    int s = t + rep*256;
    if (s < SS){
      int v = ts[s];
      bool dup = false;
      #pragma unroll 4
      for (int s2=s+1; s2<SS; ++s2) dup = dup || (ts[s2]==v);
      if (!dup) out[(size_t)b*VV + v] += pp * w[b*SS + s];
    }
  }
}

extern "C" void kernel_launch(void* const* d_in, const int* in_sizes, int n_in,
                              void* d_out, int out_size, void* d_ws, size_t ws_size,
                              hipStream_t stream)
{
  const int*   x    = (const int*)  d_in[0];
  const float* enc  = (const float*)d_in[1];
  const float* h0   = (const float*)d_in[2];
  const float* c0   = (const float*)d_in[3];
  const int*   text = (const int*)  d_in[4];
  const float* emb  = (const float*)d_in[6];
  const float* Vw   = (const float*)d_in[7];
  const float* Vb   = (const float*)d_in[8];
  const float* genw = (const float*)d_in[9];
  const float* genb = (const float*)d_in[10];
  const float* outw = (const float*)d_in[11];
  const float* outb = (const float*)d_in[12];
  const float* Wih  = (const float*)d_in[13];
  const float* Whh  = (const float*)d_in[14];
  const float* bih  = (const float*)d_in[15];
  const float* bhh  = (const float*)d_in[16];
  float* out = (float*)d_out;

  float* ws     = (float*)d_ws;
  float* score  = ws + WS_SCORE;
  float* wbuf   = ws + WS_W;
  float* ctx    = ws + WS_CTX;
  float* hnew   = ws + WS_HNEW;
  float* g0     = ws + WS_G0;
  float* g1     = ws + WS_G1;
  float* g2     = ws + WS_G2;
  float* g3     = ws + WS_G3;
  float* pgen   = ws + WS_PGEN;
  float* part   = ws + WS_PART;
  unsigned short* abf = (unsigned short*)(ws + WS_ABF);
  unsigned short* ad1 = (unsigned short*)(ws + WS_AD1);
  unsigned short* ad2 = (unsigned short*)(ws + WS_AD2);

  k_prep<<<336, 256, 0, stream>>>(x, emb, h0, ad1, ad2);
  k_score<<<6400, 256, 0, stream>>>(enc, h0, Vw, Vb, score);
  k_ctx<<<512, 256, 0, stream>>>(enc, score, wbuf, part);
  k_ctx_reduce<<<64, 256, 0, stream>>>(part, ctx, ad1);
  k_gates<<<256, 128, 0, stream>>>(Wih, Whh, ad1, ad2, g0, g1, g2, g3);
  k_lstm<<<128, 256, 0, stream>>>(c0, bih, bhh, g0, g1, g2, g3, ctx, hnew, abf, out);
  k_pgen<<<64, 256, 0, stream>>>(genw, genb, ctx, hnew, x, emb, pgen);
  k_gemm<<<1563, 128, 0, stream>>>(outw, outb, abf, pgen, out);
  k_scatter<<<64, 256, 0, stream>>>(text, wbuf, pgen, out);
}